// Round 4
// baseline (5328.191 us; speedup 1.0000x reference)
//
#include <hip/hip_runtime.h>
#include <math.h>

#define B 64
#define T 512
#define H 768
#define HEADS 4
#define DOUT 192
#define MTEXT (B*T)        // 32768
#define MSPEC (B*8)        // 512
#define MTOT (MTEXT+MSPEC)
#define CH 8               // samples per chunk
#define NCH (B/CH)         // 8 chunks
#define CTEXT (CH*T)       // 4096 text rows per chunk
#define CSPEC (CH*8)       // 64 special rows per chunk
#define CROWS_PAD (CTEXT+128)

typedef unsigned short u16;
typedef __attribute__((ext_vector_type(8))) short short8;
typedef __attribute__((ext_vector_type(4))) float floatx4;

__device__ __forceinline__ float bf2f(u16 u){
  union { float f; unsigned int i; } v; v.i = ((unsigned int)u) << 16; return v.f;
}
__device__ __forceinline__ u16 f2bf(float f){
  unsigned int u = __float_as_uint(f);
  unsigned int lsb = (u >> 16) & 1u;
  u += 0x7fffu + lsb;
  return (u16)(u >> 16);
}
__device__ __forceinline__ float lrelu(float v){ return v > 0.f ? v : 0.2f*v; }
// load element i of a raw input that is either f32 (isF32) or bf16
__device__ __forceinline__ float ldv(const void* p, size_t i, int isF32){
  return isF32 ? ((const float*)p)[i] : bf2f(((const u16*)p)[i]);
}

// ---------------- detect: input dtype from exponent-field statistics ----------------
__global__ __launch_bounds__(256) void detect_kernel(const u16* __restrict__ raw, int* __restrict__ flag){
  __shared__ int red[256];
  int tid = threadIdx.x;
  int cnt = 0;
  for (int i = tid; i < 2048; i += 256){
    u16 u = raw[(size_t)i*2];          // even u16 index: bf16 value OR f32 low-half
    int e = (u >> 7) & 0xFF;
    if (e >= 110 && e <= 135) cnt++;   // N(0,1)-plausible bf16 exponent
  }
  red[tid] = cnt; __syncthreads();
  for (int s = 128; s > 0; s >>= 1){ if (tid < s) red[tid] += red[tid+s]; __syncthreads(); }
  if (tid == 0) *flag = (red[0] < 1024) ? 1 : 0;   // 1 => inputs are float32
}

// ---------------- convert a raw param array (f32 or bf16) to bf16 ----------------
__global__ __launch_bounds__(256) void convert_kernel(const void* __restrict__ src,
                                                      u16* __restrict__ dst, int n,
                                                      const int* __restrict__ flagp){
  int i = blockIdx.x*256 + threadIdx.x;
  if (i >= n) return;
  if (*flagp) dst[i] = f2bf(((const float*)src)[i]);
  else        dst[i] = ((const u16*)src)[i];
}

// ---------------- prep: text -> xt (d_out, native dtype), specials -> xs (bf16) + norms ----------------
__global__ __launch_bounds__(256) void prep_kernel(const void* __restrict__ text,
                                                   const void* __restrict__ label,
                                                   const void* __restrict__ image,
                                                   void* __restrict__ xt,
                                                   u16* __restrict__ xs,
                                                   float* __restrict__ norms2,
                                                   const int* __restrict__ flagp){
  __shared__ float red[256];
  int isF32 = *flagp;
  int node = blockIdx.x;
  int tid = threadIdx.x;
  bool special = (node >= MTEXT);
  if (!special){
    if (isF32){
      const float* s = (const float*)text + (size_t)node*H;
      float* d = (float*)xt + (size_t)node*H;
      #pragma unroll
      for (int r = 0; r < 3; r++){ int dd = tid + r*256; d[dd] = s[dd]; }
    } else {
      const u16* s = (const u16*)text + (size_t)node*H;
      u16* d = (u16*)xt + (size_t)node*H;
      #pragma unroll
      for (int r = 0; r < 3; r++){ int dd = tid + r*256; d[dd] = s[dd]; }
    }
  } else {
    int rr = node - MTEXT;
    int b = rr >> 3, s = rr & 7;
    const void* srcb = (s < 4) ? label : image;
    size_t base = (size_t)(b*4 + (s & 3))*H;
    float sq = 0.f;
    #pragma unroll
    for (int r = 0; r < 3; r++){
      int dd = tid + r*256;
      float f = ldv(srcb, base + dd, isF32);
      xs[(size_t)rr*H + dd] = f2bf(f);
      sq += f*f;
    }
    red[tid] = sq; __syncthreads();
    for (int ss = 128; ss > 0; ss >>= 1){ if (tid < ss) red[tid] += red[tid+ss]; __syncthreads(); }
    if (tid == 0) norms2[rr] = red[0];
  }
}

// ---------------- topk: excluded (argmin) label/image index per (b,t) ----------------
__global__ __launch_bounds__(64) void topk_kernel(const void* __restrict__ text,
                                                  const void* __restrict__ label,
                                                  const void* __restrict__ image,
                                                  const float* __restrict__ norms2,
                                                  int* __restrict__ excl_l,
                                                  int* __restrict__ excl_i,
                                                  const int* __restrict__ flagp){
  int isF32 = *flagp;
  int t = blockIdx.x, b = blockIdx.y;
  int lane = threadIdx.x;
  float dl[4] = {0,0,0,0}, di[4] = {0,0,0,0};
  size_t tbase = (size_t)(b*T + t)*H;
  for (int r = 0; r < 12; r++){
    int d = lane + r*64;
    float tx = ldv(text, tbase + d, isF32);
    #pragma unroll
    for (int j = 0; j < 4; j++){
      dl[j] += tx * ldv(label, (size_t)(b*4 + j)*H + d, isF32);
      di[j] += tx * ldv(image, (size_t)(b*4 + j)*H + d, isF32);
    }
  }
  #pragma unroll
  for (int j = 0; j < 4; j++){
    for (int o = 32; o > 0; o >>= 1){
      dl[j] += __shfl_down(dl[j], o);
      di[j] += __shfl_down(di[j], o);
    }
  }
  if (lane == 0){
    float vl[4], vi[4];
    #pragma unroll
    for (int j = 0; j < 4; j++){
      vl[j] = dl[j] / fmaxf(sqrtf(norms2[b*8 + j]), 1e-8f);
      vi[j] = di[j] / fmaxf(sqrtf(norms2[b*8 + 4 + j]), 1e-8f);
    }
    int el = 0, ei = 0;
    #pragma unroll
    for (int j = 1; j < 4; j++){
      if (vl[j] <= vl[el]) el = j;   // ties -> highest index excluded (matches top_k)
      if (vi[j] <= vi[ei]) ei = j;
    }
    excl_l[b*T + t] = el;
    excl_i[b*T + t] = ei;
  }
}

// ---------------- GEMM (per chunk): h[4224,768](bf16) = x @ W^T ----------------
__global__ __launch_bounds__(256) void gemm_kernel(const void* __restrict__ xt_base, int crow0,
                                                   const u16* __restrict__ As,
                                                   const u16* __restrict__ Bw,
                                                   u16* __restrict__ C,
                                                   const int* __restrict__ flagp){
  __shared__ __align__(16) u16 lA[128*72];
  __shared__ __align__(16) u16 lB[128*72];
  int isF32 = *flagp;
  int tid = threadIdx.x;
  int tile = blockIdx.x;                 // 0..32 ; tile 32 = specials (bf16 xs)
  int mlocal = tile * 128;
  bool spec = (tile == 32);
  const u16*   Abf = (const u16*)xt_base + (size_t)(crow0 + mlocal)*H;
  const float* Af  = (const float*)xt_base + (size_t)(crow0 + mlocal)*H;
  int nbase = blockIdx.y * 128;
  int wave = tid >> 6, lane = tid & 63;
  int wm = (wave >> 1) * 64, wn = (wave & 1) * 64;
  int lrow = lane & 15, lkq = (lane >> 4) * 8;
  int r0 = tid >> 3;
  int c0 = (tid & 7) * 8;

  floatx4 acc[4][4];
  #pragma unroll
  for (int i = 0; i < 4; i++)
    #pragma unroll
    for (int j = 0; j < 4; j++)
      acc[i][j] = (floatx4){0.f,0.f,0.f,0.f};

  for (int k0 = 0; k0 < H; k0 += 64){
    short8 va[4], vb[4];
    #pragma unroll
    for (int i = 0; i < 4; i++){
      int row = i*32 + r0;
      if (spec)        va[i] = *(const short8*)(As  + (size_t)row*H + k0 + c0);
      else if (!isF32) va[i] = *(const short8*)(Abf + (size_t)row*H + k0 + c0);
      else {
        const float* p = Af + (size_t)row*H + k0 + c0;
        float4 lo = *(const float4*)p;
        float4 hi = *(const float4*)(p + 4);
        short8 tv;
        tv[0]=(short)f2bf(lo.x); tv[1]=(short)f2bf(lo.y); tv[2]=(short)f2bf(lo.z); tv[3]=(short)f2bf(lo.w);
        tv[4]=(short)f2bf(hi.x); tv[5]=(short)f2bf(hi.y); tv[6]=(short)f2bf(hi.z); tv[7]=(short)f2bf(hi.w);
        va[i] = tv;
      }
      vb[i] = *(const short8*)(Bw + (size_t)(nbase + row)*H + k0 + c0);
    }
    __syncthreads();
    #pragma unroll
    for (int i = 0; i < 4; i++){
      int row = i*32 + r0;
      *(short8*)(lA + row*72 + c0) = va[i];
      *(short8*)(lB + row*72 + c0) = vb[i];
    }
    __syncthreads();
    #pragma unroll
    for (int kk = 0; kk < 2; kk++){
      short8 af[4], bfv[4];
      #pragma unroll
      for (int i = 0; i < 4; i++){
        af[i]  = *(const short8*)(lA + (wm + i*16 + lrow)*72 + kk*32 + lkq);
        bfv[i] = *(const short8*)(lB + (wn + i*16 + lrow)*72 + kk*32 + lkq);
      }
      #pragma unroll
      for (int i = 0; i < 4; i++)
        #pragma unroll
        for (int j = 0; j < 4; j++)
          acc[i][j] = __builtin_amdgcn_mfma_f32_16x16x32_bf16(af[i], bfv[j], acc[i][j], 0, 0, 0);
    }
  }
  int qrow = (lane >> 4) * 4;
  int col = lane & 15;
  #pragma unroll
  for (int i = 0; i < 4; i++)
    #pragma unroll
    for (int j = 0; j < 4; j++)
      #pragma unroll
      for (int r = 0; r < 4; r++){
        int grow = mlocal + wm + i*16 + qrow + r;
        int gcol = nbase + wn + j*16 + col;
        C[(size_t)grow*H + gcol] = f2bf(acc[i][j][r]);
      }
}

// ---------------- fused attention (per chunk) ----------------
__global__ __launch_bounds__(256) void attn_kernel(
    const u16* __restrict__ h,
    void* __restrict__ xt_base, int crow0, u16* __restrict__ xs_c,
    const int* __restrict__ exl_c, const int* __restrict__ exi_c,
    const u16* __restrict__ a_s, const u16* __restrict__ a_d,
    const u16* __restrict__ bias, const u16* __restrict__ gamma, const u16* __restrict__ beta,
    const int* __restrict__ flagp){
  __shared__ int srcs[9];
  __shared__ int scount;
  __shared__ float esl[9][4], edl[4], alpha[9][4];
  __shared__ float red[256], red2[256];
  __shared__ float esb[512][4];
  __shared__ float sw[8][4];
  __shared__ float dinv[4];

  int isF32 = *flagp;
  u16*   xtu = (u16*)xt_base;
  float* xtf = (float*)xt_base;
  int tid = threadIdx.x, wave = tid >> 6, lane = tid & 63;

  if (blockIdx.x < CTEXT){
    // ================= text destination =================
    int loc = blockIdx.x;            // bloc*512 + t
    int bloc = loc >> 9, t = loc & 511;
    size_t xrow = (size_t)(crow0 + loc)*H;
    if (tid == 0){
      int c = 0;
      srcs[c++] = loc;
      if (t > 0)   srcs[c++] = loc - 1;
      if (t < T-1) srcs[c++] = loc + 1;
      int el = exl_c[loc];
      #pragma unroll
      for (int j = 0; j < 4; j++) if (j != el) srcs[c++] = CTEXT + bloc*8 + j;
      int ei = exi_c[loc];
      #pragma unroll
      for (int j = 0; j < 4; j++) if (j != ei) srcs[c++] = CTEXT + bloc*8 + 4 + j;
      scount = c;
    }
    __syncthreads();
    int cnt = scount;
    for (int e = wave; e < cnt; e += 4){
      const u16* hp = h + (size_t)srcs[e]*H;
      float p[4] = {0.f,0.f,0.f,0.f};
      #pragma unroll
      for (int k = 0; k < 3; k++){
        int col = lane + 64*k;
        #pragma unroll
        for (int hh = 0; hh < 4; hh++)
          p[hh] += bf2f(hp[hh*DOUT + col]) * bf2f(a_s[hh*DOUT + col]);
      }
      #pragma unroll
      for (int hh = 0; hh < 4; hh++)
        for (int o = 32; o > 0; o >>= 1) p[hh] += __shfl_down(p[hh], o);
      if (lane == 0){
        #pragma unroll
        for (int hh = 0; hh < 4; hh++) esl[e][hh] = p[hh];
      }
    }
    if (wave == 3){
      const u16* hp = h + (size_t)loc*H;
      float p[4] = {0.f,0.f,0.f,0.f};
      #pragma unroll
      for (int k = 0; k < 3; k++){
        int col = lane + 64*k;
        #pragma unroll
        for (int hh = 0; hh < 4; hh++)
          p[hh] += bf2f(hp[hh*DOUT + col]) * bf2f(a_d[hh*DOUT + col]);
      }
      #pragma unroll
      for (int hh = 0; hh < 4; hh++)
        for (int o = 32; o > 0; o >>= 1) p[hh] += __shfl_down(p[hh], o);
      if (lane == 0){
        #pragma unroll
        for (int hh = 0; hh < 4; hh++) edl[hh] = p[hh];
      }
    }
    __syncthreads();
    if (tid < 4){
      int hh = tid;
      float edv = edl[hh];
      float m = -1e30f, ev[9];
      for (int e = 0; e < cnt; e++){
        float v = lrelu(esl[e][hh] + edv);
        ev[e] = v; m = fmaxf(m, v);
      }
      float den = 0.f;
      for (int e = 0; e < cnt; e++){ ev[e] = expf(fminf(ev[e] - m, 0.f)); den += ev[e]; }
      float inv = 1.f / (den + 1e-16f);
      for (int e = 0; e < cnt; e++) alpha[e][hh] = ev[e] * inv;
    }
    __syncthreads();
    float y[3], sum = 0.f, sumsq = 0.f;
    #pragma unroll
    for (int r = 0; r < 3; r++){
      int d = tid + r*256;
      int hh = d / DOUT;
      float a = 0.f;
      for (int e = 0; e < cnt; e++)
        a += alpha[e][hh] * bf2f(h[(size_t)srcs[e]*H + d]);
      float o = fmaxf(a + bf2f(bias[d]), 0.f);
      float xv = isF32 ? xtf[xrow + d] : bf2f(xtu[xrow + d]);
      float yv = o + xv;
      y[r] = yv; sum += yv; sumsq += yv*yv;
    }
    red[tid] = sum; red2[tid] = sumsq; __syncthreads();
    for (int s = 128; s > 0; s >>= 1){
      if (tid < s){ red[tid] += red[tid+s]; red2[tid] += red2[tid+s]; }
      __syncthreads();
    }
    float mean = red[0] * (1.f/H);
    float var = red2[0] * (1.f/H) - mean*mean;
    float rstd = rsqrtf(fmaxf(var, 0.f) + 1e-5f);
    #pragma unroll
    for (int r = 0; r < 3; r++){
      int d = tid + r*256;
      float o = (y[r] - mean) * rstd * bf2f(gamma[d]) + bf2f(beta[d]);
      if (isF32) xtf[xrow + d] = o; else xtu[xrow + d] = f2bf(o);
    }
  } else {
    // ================= special destination =================
    int idx = blockIdx.x - CTEXT;    // 0..63
    int bloc = idx >> 3, s = idx & 7;
    int selfrow = CTEXT + idx;
    const int* excl = (s < 4) ? exl_c : exi_c;
    int target = s & 3;

    for (int e = wave; e < 8; e += 4){
      const u16* hp = h + (size_t)(CTEXT + bloc*8 + e)*H;
      float p[4] = {0.f,0.f,0.f,0.f};
      #pragma unroll
      for (int k = 0; k < 3; k++){
        int col = lane + 64*k;
        #pragma unroll
        for (int hh = 0; hh < 4; hh++)
          p[hh] += bf2f(hp[hh*DOUT + col]) * bf2f(a_s[hh*DOUT + col]);
      }
      #pragma unroll
      for (int hh = 0; hh < 4; hh++)
        for (int o = 32; o > 0; o >>= 1) p[hh] += __shfl_down(p[hh], o);
      if (lane == 0){
        #pragma unroll
        for (int hh = 0; hh < 4; hh++) sw[e][hh] = p[hh];
      }
    }
    if (wave == 0){
      const u16* hp = h + (size_t)selfrow*H;
      float p[4] = {0.f,0.f,0.f,0.f};
      #pragma unroll
      for (int k = 0; k < 3; k++){
        int col = lane + 64*k;
        #pragma unroll
        for (int hh = 0; hh < 4; hh++)
          p[hh] += bf2f(hp[hh*DOUT + col]) * bf2f(a_d[hh*DOUT + col]);
      }
      #pragma unroll
      for (int hh = 0; hh < 4; hh++)
        for (int o = 32; o > 0; o >>= 1) p[hh] += __shfl_down(p[hh], o);
      if (lane == 0){
        #pragma unroll
        for (int hh = 0; hh < 4; hh++) edl[hh] = p[hh];
      }
    }
    for (int t = wave; t < T; t += 4){
      const u16* hp = h + (size_t)(bloc*512 + t)*H;
      float p[4] = {0.f,0.f,0.f,0.f};
      #pragma unroll
      for (int k = 0; k < 3; k++){
        int col = lane + 64*k;
        #pragma unroll
        for (int hh = 0; hh < 4; hh++)
          p[hh] += bf2f(hp[hh*DOUT + col]) * bf2f(a_s[hh*DOUT + col]);
      }
      #pragma unroll
      for (int hh = 0; hh < 4; hh++)
        for (int o = 32; o > 0; o >>= 1) p[hh] += __shfl_down(p[hh], o);
      if (lane == 0){
        #pragma unroll
        for (int hh = 0; hh < 4; hh++) esb[t][hh] = p[hh];
      }
    }
    __syncthreads();
    float edv[4];
    #pragma unroll
    for (int hh = 0; hh < 4; hh++) edv[hh] = edl[hh];

    float m[4] = {-1e30f,-1e30f,-1e30f,-1e30f};
    #pragma unroll
    for (int q = 0; q < 2; q++){
      int t = tid + q*256;
      if (excl[bloc*512 + t] != target){
        #pragma unroll
        for (int hh = 0; hh < 4; hh++)
          m[hh] = fmaxf(m[hh], lrelu(esb[t][hh] + edv[hh]));
      }
    }
    if (tid < 8){
      #pragma unroll
      for (int hh = 0; hh < 4; hh++)
        m[hh] = fmaxf(m[hh], lrelu(sw[tid][hh] + edv[hh]));
    }
    #pragma unroll
    for (int hh = 0; hh < 4; hh++){
      red[tid] = m[hh]; __syncthreads();
      for (int ss = 128; ss > 0; ss >>= 1){
        if (tid < ss) red[tid] = fmaxf(red[tid], red[tid+ss]);
        __syncthreads();
      }
      m[hh] = red[0]; __syncthreads();
    }
    float dsum[4] = {0.f,0.f,0.f,0.f};
    #pragma unroll
    for (int q = 0; q < 2; q++){
      int t = tid + q*256;
      bool sel = (excl[bloc*512 + t] != target);
      #pragma unroll
      for (int hh = 0; hh < 4; hh++){
        float w = 0.f;
        if (sel) w = expf(fminf(lrelu(esb[t][hh] + edv[hh]) - m[hh], 0.f));
        esb[t][hh] = w;
        dsum[hh] += w;
      }
    }
    if (tid < 8){
      #pragma unroll
      for (int hh = 0; hh < 4; hh++){
        float w = expf(fminf(lrelu(sw[tid][hh] + edv[hh]) - m[hh], 0.f));
        sw[tid][hh] = w;
        dsum[hh] += w;
      }
    }
    #pragma unroll
    for (int hh = 0; hh < 4; hh++){
      red[tid] = dsum[hh]; __syncthreads();
      for (int ss = 128; ss > 0; ss >>= 1){
        if (tid < ss) red[tid] += red[tid+ss];
        __syncthreads();
      }
      if (tid == 0) dinv[hh] = 1.f / (red[0] + 1e-16f);
      __syncthreads();
    }
    int dd[3], hh4[3];
    #pragma unroll
    for (int r = 0; r < 3; r++){ dd[r] = tid + r*256; hh4[r] = dd[r] / DOUT; }
    float agg[3] = {0.f,0.f,0.f};
    for (int t = 0; t < T; t++){
      const u16* hp = h + (size_t)(bloc*512 + t)*H;
      #pragma unroll
      for (int r = 0; r < 3; r++)
        agg[r] += esb[t][hh4[r]] * bf2f(hp[dd[r]]);
    }
    #pragma unroll
    for (int e = 0; e < 8; e++){
      const u16* hp = h + (size_t)(CTEXT + bloc*8 + e)*H;
      #pragma unroll
      for (int r = 0; r < 3; r++)
        agg[r] += sw[e][hh4[r]] * bf2f(hp[dd[r]]);
    }
    float y[3], sum = 0.f, sumsq = 0.f;
    #pragma unroll
    for (int r = 0; r < 3; r++){
      float a = agg[r] * dinv[hh4[r]];
      float o = fmaxf(a + bf2f(bias[dd[r]]), 0.f);
      float yv = o + bf2f(xs_c[(size_t)idx*H + dd[r]]);
      y[r] = yv; sum += yv; sumsq += yv*yv;
    }
    red[tid] = sum; red2[tid] = sumsq; __syncthreads();
    for (int ss = 128; ss > 0; ss >>= 1){
      if (tid < ss){ red[tid] += red[tid+ss]; red2[tid] += red2[tid+ss]; }
      __syncthreads();
    }
    float mean = red[0] * (1.f/H);
    float var = red2[0] * (1.f/H) - mean*mean;
    float rstd = rsqrtf(fmaxf(var, 0.f) + 1e-5f);
    #pragma unroll
    for (int r = 0; r < 3; r++){
      float o = (y[r] - mean) * rstd * bf2f(gamma[dd[r]]) + bf2f(beta[dd[r]]);
      xs_c[(size_t)idx*H + dd[r]] = f2bf(o);
    }
  }
}

extern "C" void kernel_launch(void* const* d_in, const int* in_sizes, int n_in,
                              void* d_out, int out_size, void* d_ws, size_t ws_size,
                              hipStream_t stream){
  const void* text   = d_in[0];
  const void* label  = d_in[1];
  const void* image  = d_in[2];

  char* ws = (char*)d_ws;
  size_t off = 0;
  auto alloc = [&](size_t bytes) -> void* {
    void* p = ws + off; off += (bytes + 255) & ~(size_t)255; return p;
  };
  int*   flag = (int*)  alloc(4);
  u16*   h    = (u16*)  alloc((size_t)CROWS_PAD*768*2);  // 6.5 MB
  u16*   xs   = (u16*)  alloc((size_t)(MSPEC+64)*768*2); // 0.9 MB
  int*   exl  = (int*)  alloc((size_t)B*T*4);
  int*   exi  = (int*)  alloc((size_t)B*T*4);
  float* nrm  = (float*)alloc((size_t)B*8*4);
  u16*   Wc   = (u16*)  alloc((size_t)3*768*768*2);      // 3.5 MB
  u16*   asc  = (u16*)  alloc((size_t)3*768*2);
  u16*   adc  = (u16*)  alloc((size_t)3*768*2);
  u16*   bc   = (u16*)  alloc((size_t)3*768*2);
  u16*   gc   = (u16*)  alloc((size_t)3*768*2);
  u16*   bec  = (u16*)  alloc((size_t)3*768*2);

  detect_kernel<<<1, 256, 0, stream>>>((const u16*)text, flag);
  convert_kernel<<<(3*768*768 + 255)/256, 256, 0, stream>>>(d_in[3], Wc, 3*768*768, flag);
  convert_kernel<<<9, 256, 0, stream>>>(d_in[4], asc, 3*768, flag);
  convert_kernel<<<9, 256, 0, stream>>>(d_in[5], adc, 3*768, flag);
  convert_kernel<<<9, 256, 0, stream>>>(d_in[6], bc,  3*768, flag);
  convert_kernel<<<9, 256, 0, stream>>>(d_in[7], gc,  3*768, flag);
  convert_kernel<<<9, 256, 0, stream>>>(d_in[8], bec, 3*768, flag);

  prep_kernel<<<MTOT, 256, 0, stream>>>(text, label, image, d_out, xs, nrm, flag);
  topk_kernel<<<dim3(T, B), 64, 0, stream>>>(text, label, image, nrm, exl, exi, flag);
  for (int l = 0; l < 3; l++){
    for (int c = 0; c < NCH; c++){
      gemm_kernel<<<dim3(33, 6), 256, 0, stream>>>(
          d_out, c*CTEXT, xs + (size_t)c*CSPEC*768, Wc + (size_t)l*768*768, h, flag);
      attn_kernel<<<CTEXT + CSPEC, 256, 0, stream>>>(
          h, d_out, c*CTEXT, xs + (size_t)c*CSPEC*768,
          exl + c*CTEXT, exi + c*CTEXT,
          asc + l*768, adc + l*768, bc + l*768, gc + l*768, bec + l*768, flag);
    }
  }
  // final text state lives in d_out (native dtype); no writeout needed
}

// Round 5
// 1320.690 us; speedup vs baseline: 4.0344x; 4.0344x over previous
//
#include <hip/hip_runtime.h>
#include <math.h>

#define B 64
#define T 512
#define H 768
#define DOUT 192
#define MTEXT (B*T)        // 32768
#define MSPEC (B*8)        // 512

typedef unsigned short u16;
typedef __attribute__((ext_vector_type(8))) short short8;
typedef __attribute__((ext_vector_type(4))) float floatx4;

__device__ __forceinline__ float bf2f(u16 u){
  union { float f; unsigned int i; } v; v.i = ((unsigned int)u) << 16; return v.f;
}
__device__ __forceinline__ u16 f2bf(float f){
  unsigned int u = __float_as_uint(f);
  unsigned int lsb = (u >> 16) & 1u;
  u += 0x7fffu + lsb;
  return (u16)(u >> 16);
}
__device__ __forceinline__ float lrelu(float v){ return v > 0.f ? v : 0.2f*v; }
__device__ __forceinline__ float ldv(const void* p, size_t i, int isF32){
  return isF32 ? ((const float*)p)[i] : bf2f(((const u16*)p)[i]);
}

// ---------------- detect input dtype ----------------
__global__ __launch_bounds__(256) void detect_kernel(const u16* __restrict__ raw, int* __restrict__ flag){
  __shared__ int red[256];
  int tid = threadIdx.x;
  int cnt = 0;
  for (int i = tid; i < 2048; i += 256){
    u16 u = raw[(size_t)i*2];
    int e = (u >> 7) & 0xFF;
    if (e >= 110 && e <= 135) cnt++;
  }
  red[tid] = cnt; __syncthreads();
  for (int s = 128; s > 0; s >>= 1){ if (tid < s) red[tid] += red[tid+s]; __syncthreads(); }
  if (tid == 0) *flag = (red[0] < 1024) ? 1 : 0;   // 1 => float32 inputs
}

// ---------------- convert raw param (f32 or bf16) -> bf16 ----------------
__global__ __launch_bounds__(256) void convert_kernel(const void* __restrict__ src,
                                                      u16* __restrict__ dst, int n,
                                                      const int* __restrict__ flagp){
  int i = blockIdx.x*256 + threadIdx.x;
  if (i >= n) return;
  if (*flagp) dst[i] = f2bf(((const float*)src)[i]);
  else        dst[i] = ((const u16*)src)[i];
}

// ---------------- prep specials: label/image -> xs (bf16) + sq-norms ----------------
__global__ __launch_bounds__(256) void prep_spec_kernel(const void* __restrict__ label,
                                                        const void* __restrict__ image,
                                                        u16* __restrict__ xs,
                                                        float* __restrict__ norms2,
                                                        const int* __restrict__ flagp){
  __shared__ float red[256];
  int isF32 = *flagp;
  int rr = blockIdx.x;          // 0..511
  int tid = threadIdx.x;
  int b = rr >> 3, s = rr & 7;
  const void* srcb = (s < 4) ? label : image;
  size_t base = (size_t)(b*4 + (s & 3))*H;
  float sq = 0.f;
  #pragma unroll
  for (int r = 0; r < 3; r++){
    int dd = tid + r*256;
    float f = ldv(srcb, base + dd, isF32);
    xs[(size_t)rr*H + dd] = f2bf(f);
    sq += f*f;
  }
  red[tid] = sq; __syncthreads();
  for (int ss = 128; ss > 0; ss >>= 1){ if (tid < ss) red[tid] += red[tid+ss]; __syncthreads(); }
  if (tid == 0) norms2[rr] = red[0];
}

// ---------------- topk: excluded (argmin) label/image index per (b,t) ----------------
__global__ __launch_bounds__(64) void topk_kernel(const void* __restrict__ text,
                                                  const void* __restrict__ label,
                                                  const void* __restrict__ image,
                                                  const float* __restrict__ norms2,
                                                  int* __restrict__ excl_l,
                                                  int* __restrict__ excl_i,
                                                  const int* __restrict__ flagp){
  int isF32 = *flagp;
  int t = blockIdx.x, b = blockIdx.y;
  int lane = threadIdx.x;
  float dl[4] = {0,0,0,0}, di[4] = {0,0,0,0};
  size_t tbase = (size_t)(b*T + t)*H;
  for (int r = 0; r < 12; r++){
    int d = lane + r*64;
    float tx = ldv(text, tbase + d, isF32);
    #pragma unroll
    for (int j = 0; j < 4; j++){
      dl[j] += tx * ldv(label, (size_t)(b*4 + j)*H + d, isF32);
      di[j] += tx * ldv(image, (size_t)(b*4 + j)*H + d, isF32);
    }
  }
  #pragma unroll
  for (int j = 0; j < 4; j++){
    for (int o = 32; o > 0; o >>= 1){
      dl[j] += __shfl_down(dl[j], o);
      di[j] += __shfl_down(di[j], o);
    }
  }
  if (lane == 0){
    float vl[4], vi[4];
    #pragma unroll
    for (int j = 0; j < 4; j++){
      vl[j] = dl[j] / fmaxf(sqrtf(norms2[b*8 + j]), 1e-8f);
      vi[j] = di[j] / fmaxf(sqrtf(norms2[b*8 + 4 + j]), 1e-8f);
    }
    int el = 0, ei = 0;
    #pragma unroll
    for (int j = 1; j < 4; j++){
      if (vl[j] <= vl[el]) el = j;
      if (vi[j] <= vi[ei]) ei = j;
    }
    excl_l[b*T + t] = el;
    excl_i[b*T + t] = ei;
  }
}

// ---------------- GEMM: h[hrows,768](bf16) = x @ W^T ----------------
__global__ __launch_bounds__(256) void gemm_kernel(const void* __restrict__ At, int arow0,
                                                   const u16* __restrict__ As,
                                                   const u16* __restrict__ Bw,
                                                   u16* __restrict__ C,
                                                   int text_tiles, int ctext,
                                                   const int* __restrict__ flagp){
  __shared__ __align__(16) u16 lA[128*72];
  __shared__ __align__(16) u16 lB[128*72];
  int isF32 = *flagp;
  int tid = threadIdx.x;
  int tile = blockIdx.x;
  bool spec = (tile >= text_tiles);
  int lrow0 = spec ? (tile - text_tiles)*128 : tile*128;
  int crow0 = spec ? (ctext + lrow0) : lrow0;
  const u16*   Abf = spec ? (As + (size_t)lrow0*H)
                          : ((const u16*)At + (size_t)(arow0 + lrow0)*H);
  const float* Af  = (const float*)At + (size_t)(arow0 + lrow0)*H;
  int nbase = blockIdx.y * 128;
  int wave = tid >> 6, lane = tid & 63;
  int wm = (wave >> 1) * 64, wn = (wave & 1) * 64;
  int lrow = lane & 15, lkq = (lane >> 4) * 8;
  int r0 = tid >> 3;
  int c0 = (tid & 7) * 8;

  floatx4 acc[4][4];
  #pragma unroll
  for (int i = 0; i < 4; i++)
    #pragma unroll
    for (int j = 0; j < 4; j++)
      acc[i][j] = (floatx4){0.f,0.f,0.f,0.f};

  for (int k0 = 0; k0 < H; k0 += 64){
    short8 va[4], vb[4];
    #pragma unroll
    for (int i = 0; i < 4; i++){
      int row = i*32 + r0;
      if (spec || !isF32) va[i] = *(const short8*)(Abf + (size_t)row*H + k0 + c0);
      else {
        const float* p = Af + (size_t)row*H + k0 + c0;
        float4 lo = *(const float4*)p;
        float4 hi = *(const float4*)(p + 4);
        short8 tv;
        tv[0]=(short)f2bf(lo.x); tv[1]=(short)f2bf(lo.y); tv[2]=(short)f2bf(lo.z); tv[3]=(short)f2bf(lo.w);
        tv[4]=(short)f2bf(hi.x); tv[5]=(short)f2bf(hi.y); tv[6]=(short)f2bf(hi.z); tv[7]=(short)f2bf(hi.w);
        va[i] = tv;
      }
      vb[i] = *(const short8*)(Bw + (size_t)(nbase + row)*H + k0 + c0);
    }
    __syncthreads();
    #pragma unroll
    for (int i = 0; i < 4; i++){
      int row = i*32 + r0;
      *(short8*)(lA + row*72 + c0) = va[i];
      *(short8*)(lB + row*72 + c0) = vb[i];
    }
    __syncthreads();
    #pragma unroll
    for (int kk = 0; kk < 2; kk++){
      short8 af[4], bfv[4];
      #pragma unroll
      for (int i = 0; i < 4; i++){
        af[i]  = *(const short8*)(lA + (wm + i*16 + lrow)*72 + kk*32 + lkq);
        bfv[i] = *(const short8*)(lB + (wn + i*16 + lrow)*72 + kk*32 + lkq);
      }
      #pragma unroll
      for (int i = 0; i < 4; i++)
        #pragma unroll
        for (int j = 0; j < 4; j++)
          acc[i][j] = __builtin_amdgcn_mfma_f32_16x16x32_bf16(af[i], bfv[j], acc[i][j], 0, 0, 0);
    }
  }
  int qrow = (lane >> 4) * 4;
  int col = lane & 15;
  #pragma unroll
  for (int i = 0; i < 4; i++)
    #pragma unroll
    for (int j = 0; j < 4; j++)
      #pragma unroll
      for (int r = 0; r < 4; r++){
        int grow = crow0 + wm + i*16 + qrow + r;
        int gcol = nbase + wn + j*16 + col;
        C[(size_t)grow*H + gcol] = f2bf(acc[i][j][r]);
      }
}

// ---------------- per-node es/ed (one block per node, no barriers) ----------------
__global__ __launch_bounds__(256) void node_att_kernel(const u16* __restrict__ h,
                                                       const u16* __restrict__ a_s,
                                                       const u16* __restrict__ a_d,
                                                       float* __restrict__ es,
                                                       float* __restrict__ ed){
  int node = blockIdx.x;
  int head = threadIdx.x >> 6, lane = threadIdx.x & 63;
  const u16* hp = h + (size_t)node*H + head*DOUT;
  float s = 0.f, d = 0.f;
  #pragma unroll
  for (int k = 0; k < 3; k++){
    float hv = bf2f(hp[lane + k*64]);
    s += hv * bf2f(a_s[head*DOUT + lane + k*64]);
    d += hv * bf2f(a_d[head*DOUT + lane + k*64]);
  }
  for (int o = 32; o > 0; o >>= 1){ s += __shfl_down(s, o); d += __shfl_down(d, o); }
  if (lane == 0){ es[node*4 + head] = s; ed[node*4 + head] = d; }
}

// ---------------- fused attention: specials first, then text ----------------
__global__ __launch_bounds__(256) void attn_kernel(
    const u16* __restrict__ h,
    const void* __restrict__ xprev, int xrow0, void* __restrict__ xout,
    u16* __restrict__ xs_c,
    const float* __restrict__ es, const float* __restrict__ ed,
    const int* __restrict__ exl_c, const int* __restrict__ exi_c,
    const u16* __restrict__ bias, const u16* __restrict__ gamma, const u16* __restrict__ beta,
    int ctext, int cspec, const int* __restrict__ flagp){
  __shared__ float wred[16];
  __shared__ int srcs[9];
  __shared__ int scnt;
  __shared__ float alpha[9][4];
  __shared__ float wdyn[512][4];
  __shared__ float sw[8][4];
  __shared__ float wm4[4][4], wsum4[4][4];

  int isF32 = *flagp;
  int tid = threadIdx.x, wave = tid >> 6, lane = tid & 63;

  if ((int)blockIdx.x >= cspec){
    // ================= text destination =================
    int loc = blockIdx.x - cspec;
    int bloc = loc >> 9, t = loc & 511;
    if (tid == 0){
      int c = 0;
      srcs[c++] = loc;
      if (t > 0)   srcs[c++] = loc - 1;
      if (t < T-1) srcs[c++] = loc + 1;
      int el = exl_c[loc];
      #pragma unroll
      for (int j = 0; j < 4; j++) if (j != el) srcs[c++] = ctext + bloc*8 + j;
      int ei = exi_c[loc];
      #pragma unroll
      for (int j = 0; j < 4; j++) if (j != ei) srcs[c++] = ctext + bloc*8 + 4 + j;
      scnt = c;
    }
    __syncthreads();
    int cnt = scnt;
    if (tid < 4){
      int hh = tid;
      float edv = ed[loc*4 + hh];
      float m = -1e30f, ev[9];
      for (int e = 0; e < cnt; e++){
        float v = lrelu(es[srcs[e]*4 + hh] + edv);
        ev[e] = v; m = fmaxf(m, v);
      }
      float den = 0.f;
      for (int e = 0; e < cnt; e++){ ev[e] = expf(fminf(ev[e] - m, 0.f)); den += ev[e]; }
      float inv = 1.f / (den + 1e-16f);
      for (int e = 0; e < cnt; e++) alpha[e][hh] = ev[e] * inv;
    }
    __syncthreads();
    float y[3], sum = 0.f, sumsq = 0.f;
    #pragma unroll
    for (int r = 0; r < 3; r++){
      int d = tid + r*256;
      int hh = d / DOUT;
      float a = 0.f;
      for (int e = 0; e < cnt; e++)
        a += alpha[e][hh] * bf2f(h[(size_t)srcs[e]*H + d]);
      float o = fmaxf(a + bf2f(bias[d]), 0.f);
      float xv = isF32 ? ((const float*)xprev)[(size_t)(xrow0 + loc)*H + d]
                       : bf2f(((const u16*)xprev)[(size_t)(xrow0 + loc)*H + d]);
      float yv = o + xv;
      y[r] = yv; sum += yv; sumsq += yv*yv;
    }
    for (int o = 32; o > 0; o >>= 1){ sum += __shfl_down(sum, o); sumsq += __shfl_down(sumsq, o); }
    if (lane == 0){ wred[wave] = sum; wred[8 + wave] = sumsq; }
    __syncthreads();
    sum   = wred[0] + wred[1] + wred[2] + wred[3];
    sumsq = wred[8] + wred[9] + wred[10] + wred[11];
    float mean = sum * (1.f/H);
    float var = sumsq * (1.f/H) - mean*mean;
    float rstd = rsqrtf(fmaxf(var, 0.f) + 1e-5f);
    #pragma unroll
    for (int r = 0; r < 3; r++){
      int d = tid + r*256;
      float o = (y[r] - mean) * rstd * bf2f(gamma[d]) + bf2f(beta[d]);
      if (isF32) ((float*)xout)[(size_t)(xrow0 + loc)*H + d] = o;
      else       ((u16*)xout)[(size_t)(xrow0 + loc)*H + d] = f2bf(o);
    }
  } else {
    // ================= special destination =================
    int idx = blockIdx.x;
    int bloc = idx >> 3, s = idx & 7;
    int node = ctext + idx;
    const int* excl = (s < 4) ? exl_c : exi_c;
    int target = s & 3;
    float edv[4];
    #pragma unroll
    for (int hh = 0; hh < 4; hh++) edv[hh] = ed[node*4 + hh];

    int t0 = tid, t1 = tid + 256;
    bool sel0 = (excl[bloc*512 + t0] != target);
    bool sel1 = (excl[bloc*512 + t1] != target);
    const float* e0 = es + (size_t)(bloc*512 + t0)*4;
    const float* e1 = es + (size_t)(bloc*512 + t1)*4;
    float v0[4], v1[4], vs[4], m[4];
    #pragma unroll
    for (int hh = 0; hh < 4; hh++){
      v0[hh] = sel0 ? lrelu(e0[hh] + edv[hh]) : -1e30f;
      v1[hh] = sel1 ? lrelu(e1[hh] + edv[hh]) : -1e30f;
      m[hh] = fmaxf(v0[hh], v1[hh]);
    }
    if (tid < 8){
      const float* ep = es + (size_t)(ctext + bloc*8 + tid)*4;
      #pragma unroll
      for (int hh = 0; hh < 4; hh++){ vs[hh] = lrelu(ep[hh] + edv[hh]); m[hh] = fmaxf(m[hh], vs[hh]); }
    }
    #pragma unroll
    for (int hh = 0; hh < 4; hh++)
      for (int o = 32; o > 0; o >>= 1) m[hh] = fmaxf(m[hh], __shfl_down(m[hh], o));
    if (lane == 0){
      #pragma unroll
      for (int hh = 0; hh < 4; hh++) wm4[wave][hh] = m[hh];
    }
    __syncthreads();
    #pragma unroll
    for (int hh = 0; hh < 4; hh++)
      m[hh] = fmaxf(fmaxf(wm4[0][hh], wm4[1][hh]), fmaxf(wm4[2][hh], wm4[3][hh]));

    float ds[4];
    #pragma unroll
    for (int hh = 0; hh < 4; hh++){
      float w0 = sel0 ? expf(fminf(v0[hh] - m[hh], 0.f)) : 0.f;
      float w1 = sel1 ? expf(fminf(v1[hh] - m[hh], 0.f)) : 0.f;
      wdyn[t0][hh] = w0; wdyn[t1][hh] = w1;
      ds[hh] = w0 + w1;
    }
    if (tid < 8){
      #pragma unroll
      for (int hh = 0; hh < 4; hh++){
        float w = expf(fminf(vs[hh] - m[hh], 0.f));
        sw[tid][hh] = w; ds[hh] += w;
      }
    }
    #pragma unroll
    for (int hh = 0; hh < 4; hh++)
      for (int o = 32; o > 0; o >>= 1) ds[hh] += __shfl_down(ds[hh], o);
    if (lane == 0){
      #pragma unroll
      for (int hh = 0; hh < 4; hh++) wsum4[wave][hh] = ds[hh];
    }
    __syncthreads();   // also makes wdyn/sw visible
    float dinv[4];
    #pragma unroll
    for (int hh = 0; hh < 4; hh++)
      dinv[hh] = 1.f / (wsum4[0][hh] + wsum4[1][hh] + wsum4[2][hh] + wsum4[3][hh] + 1e-16f);

    int dd[3], hh4[3];
    #pragma unroll
    for (int r = 0; r < 3; r++){ dd[r] = tid + r*256; hh4[r] = dd[r] / DOUT; }
    float agg[3] = {0.f, 0.f, 0.f};
    const u16* hbase = h + (size_t)(bloc*512)*H;
    #pragma unroll 8
    for (int t = 0; t < 512; t++){
      #pragma unroll
      for (int r = 0; r < 3; r++)
        agg[r] += wdyn[t][hh4[r]] * bf2f(hbase[(size_t)t*H + dd[r]]);
    }
    #pragma unroll
    for (int e = 0; e < 8; e++){
      const u16* hp = h + (size_t)(ctext + bloc*8 + e)*H;
      #pragma unroll
      for (int r = 0; r < 3; r++)
        agg[r] += sw[e][hh4[r]] * bf2f(hp[dd[r]]);
    }
    float y[3], sum = 0.f, sumsq = 0.f;
    #pragma unroll
    for (int r = 0; r < 3; r++){
      float a = agg[r] * dinv[hh4[r]];
      float o = fmaxf(a + bf2f(bias[dd[r]]), 0.f);
      float yv = o + bf2f(xs_c[(size_t)idx*H + dd[r]]);
      y[r] = yv; sum += yv; sumsq += yv*yv;
    }
    for (int o = 32; o > 0; o >>= 1){ sum += __shfl_down(sum, o); sumsq += __shfl_down(sumsq, o); }
    if (lane == 0){ wred[wave] = sum; wred[8 + wave] = sumsq; }
    __syncthreads();
    sum   = wred[0] + wred[1] + wred[2] + wred[3];
    sumsq = wred[8] + wred[9] + wred[10] + wred[11];
    float mean = sum * (1.f/H);
    float var = sumsq * (1.f/H) - mean*mean;
    float rstd = rsqrtf(fmaxf(var, 0.f) + 1e-5f);
    #pragma unroll
    for (int r = 0; r < 3; r++){
      float o = (y[r] - mean) * rstd * bf2f(gamma[dd[r]]) + bf2f(beta[dd[r]]);
      xs_c[(size_t)idx*H + dd[r]] = f2bf(o);
    }
  }
}

extern "C" void kernel_launch(void* const* d_in, const int* in_sizes, int n_in,
                              void* d_out, int out_size, void* d_ws, size_t ws_size,
                              hipStream_t stream){
  const void* text  = d_in[0];
  const void* label = d_in[1];
  const void* image = d_in[2];

  auto align256 = [](size_t x){ return (x + 255) & ~(size_t)255; };

  // pick chunk count from ws_size (deterministic -> graph-safe)
  int nch = 8, ctext = MTEXT/8, cspec = MSPEC/8, spec_tiles = 1, hrows = 0;
  for (int cand = 1; cand <= 8; cand <<= 1){
    int ct = MTEXT/cand, cs = MSPEC/cand;
    int st = (cs + 127)/128;
    int hr = ct + st*128;
    size_t need = align256(4)
                + align256((size_t)hr*H*2)
                + align256((size_t)(MSPEC+64)*H*2)
                + 2*align256((size_t)MTEXT*4)
                + align256((size_t)MSPEC*4)
                + 2*align256((size_t)hr*4*4)
                + align256((size_t)3*H*H*2)
                + 5*align256((size_t)3*H*2);
    if (need <= ws_size || cand == 8){
      nch = cand; ctext = ct; cspec = cs; spec_tiles = st; hrows = hr;
      break;
    }
  }
  int text_tiles = ctext / 128;

  char* ws = (char*)d_ws;
  size_t off = 0;
  auto alloc = [&](size_t bytes) -> void* {
    void* p = ws + off; off += (bytes + 255) & ~(size_t)255; return p;
  };
  int*   flag = (int*)  alloc(4);
  u16*   h    = (u16*)  alloc((size_t)hrows*H*2);
  u16*   xs   = (u16*)  alloc((size_t)(MSPEC+64)*H*2);
  int*   exl  = (int*)  alloc((size_t)MTEXT*4);
  int*   exi  = (int*)  alloc((size_t)MTEXT*4);
  float* nrm  = (float*)alloc((size_t)MSPEC*4);
  float* es   = (float*)alloc((size_t)hrows*4*4);
  float* ed   = (float*)alloc((size_t)hrows*4*4);
  u16*   Wc   = (u16*)  alloc((size_t)3*H*H*2);
  u16*   asc  = (u16*)  alloc((size_t)3*H*2);
  u16*   adc  = (u16*)  alloc((size_t)3*H*2);
  u16*   bc   = (u16*)  alloc((size_t)3*H*2);
  u16*   gc   = (u16*)  alloc((size_t)3*H*2);
  u16*   bec  = (u16*)  alloc((size_t)3*H*2);

  detect_kernel<<<1, 256, 0, stream>>>((const u16*)text, flag);
  convert_kernel<<<(3*H*H + 255)/256, 256, 0, stream>>>(d_in[3], Wc, 3*H*H, flag);
  convert_kernel<<<9, 256, 0, stream>>>(d_in[4], asc, 3*H, flag);
  convert_kernel<<<9, 256, 0, stream>>>(d_in[5], adc, 3*H, flag);
  convert_kernel<<<9, 256, 0, stream>>>(d_in[6], bc,  3*H, flag);
  convert_kernel<<<9, 256, 0, stream>>>(d_in[7], gc,  3*H, flag);
  convert_kernel<<<9, 256, 0, stream>>>(d_in[8], bec, 3*H, flag);

  prep_spec_kernel<<<MSPEC, 256, 0, stream>>>(label, image, xs, nrm, flag);
  topk_kernel<<<dim3(T, B), 64, 0, stream>>>(text, label, image, nrm, exl, exi, flag);

  for (int l = 0; l < 3; l++){
    const void* xprev = (l == 0) ? text : (const void*)d_out;
    for (int c = 0; c < nch; c++){
      gemm_kernel<<<dim3(text_tiles + spec_tiles, 6), 256, 0, stream>>>(
          xprev, c*ctext, xs + (size_t)c*cspec*H, Wc + (size_t)l*H*H, h,
          text_tiles, ctext, flag);
      node_att_kernel<<<ctext + cspec, 256, 0, stream>>>(
          h, asc + l*H, adc + l*H, es, ed);
      attn_kernel<<<ctext + cspec, 256, 0, stream>>>(
          h, xprev, c*ctext, d_out, xs + (size_t)c*cspec*H,
          es, ed, exl + c*ctext, exi + c*ctext,
          bc + l*H, gc + l*H, bec + l*H,
          ctext, cspec, flag);
    }
  }
}